// Round 9
// baseline (1662.636 us; speedup 1.0000x reference)
//
#include <hip/hip_runtime.h>
#include <stdint.h>
#include <math.h>

constexpr int NPG = 32768;
constexpr int NGRAPH = 128;
constexpr int L1 = 5, L2 = 64, L3 = 32, L4 = 8;
constexpr int K1 = 328, K2 = 33, K3 = 4;

// diagnostic repeat counts (idempotent re-execution; state identical to R=1)
constexpr int R_SCORE = 8, R_SEL = 32, R_MLP = 32;

__device__ __forceinline__ uint32_t mono(float f) {
  uint32_t u = __float_as_uint(f);
  return (u & 0x80000000u) ? ~u : (u | 0x80000000u);
}
__device__ __forceinline__ float imono(uint32_t k) {
  uint32_t u = (k & 0x80000000u) ? (k ^ 0x80000000u) : ~k;
  return __uint_as_float(u);
}

// wave-0: pick threshold bucket from nb-bin histogram (suffix scan from top).
__device__ __forceinline__ void pick_bucket(const uint32_t* hist, int nb, int bits,
                                            uint32_t* s_prefix, int* s_rem,
                                            int* s_nc, int tid) {
  if (tid < 64) {
    const int chunk = (nb >= 64) ? (nb >> 6) : 1;
    const int nlane = (nb >= 64) ? 64 : nb;
    const int base = tid * chunk;
    uint32_t S = 0;
    if (tid < nlane)
      for (int b = 0; b < chunk; ++b) S += hist[base + b];
    uint32_t incl = S;
    for (int d = 1; d < 64; d <<= 1) {
      uint32_t t = __shfl_down(incl, d);
      if (tid + d < 64) incl += t;
    }
    uint32_t above = incl - S;
    uint32_t rem = (uint32_t)*s_rem;
    if (tid < nlane && above < rem && rem <= incl) {  // exactly one winner
      uint32_t cum = above;
      for (int b = chunk - 1; b >= 0; --b) {
        uint32_t h = hist[base + b];
        if (cum + h >= rem) {
          int rnew = (int)(rem - cum);
          *s_rem = rnew;
          *s_nc = (K1 - rnew) + (int)h;
          *s_prefix = (*s_prefix << bits) | (uint32_t)(base + b);
          break;
        }
        cum += h;
      }
    }
  }
}

// ---- kernel 1: DENSE score stream (r8-identical math), repeated R times ----
__global__ __launch_bounds__(256) void score_kernel(
    const float* __restrict__ x, const float* __restrict__ w1,
    uint32_t* __restrict__ key32, int R) {
  __shared__ __align__(16) float sb[2048 * L1];   // 40 KB
  const int tid = threadIdx.x;
  const int g = blockIdx.x >> 4;
  const int bg = blockIdx.x & 15;
  const float w10 = w1[0], w11 = w1[1], w12 = w1[2], w13 = w1[3], w14 = w1[4];
  const float4* src = (const float4*)(x + ((size_t)g * NPG + bg * 2048) * L1);
  uint32_t* kg = key32 + (size_t)g * (NPG / 2) + bg * 1024;
  for (int rep = 0; rep < R; ++rep) {
#pragma unroll
    for (int k = 0; k < 10; ++k)
      ((float4*)sb)[tid + 256 * k] = src[tid + 256 * k];
    __syncthreads();
#pragma unroll
    for (int p = 0; p < 4; ++p) {
      const int np = tid + 256 * p;                 // node pair
      const float* r = sb + np * 10;
      float d0 = r[0]*w10 + r[1]*w11 + r[2]*w12 + r[3]*w13 + r[4]*w14;
      float d1 = r[5]*w10 + r[6]*w11 + r[7]*w12 + r[8]*w13 + r[9]*w14;
      kg[np] = (mono(d0) >> 16) | (mono(d1) & 0xFFFF0000u);
    }
    __syncthreads();   // WAR: protect sb before next rep's stage
  }
}

// ---- kernel 2: selection only (hist -> threshold -> collect -> rank) ----
__global__ __launch_bounds__(1024, 1) void select_kernel(
    const float* __restrict__ x, const uint16_t* __restrict__ key16,
    const float* __restrict__ w1, unsigned long long* __restrict__ selg, int R) {
  __shared__ uint32_t whist[16 * 264];                      // per-wave hists
  __shared__ uint32_t hist256[256];
  __shared__ __align__(16) unsigned long long comp[1024];
  __shared__ __align__(16) unsigned long long sorted[512];
  __shared__ uint32_t s_prefix;
  __shared__ int s_rem, s_nc, s_cnt;

  const int tid = threadIdx.x;
  const int wid = tid >> 6;
  const int g = blockIdx.x;
  const float* xg = x + (size_t)g * NPG * L1;
  const uint16_t* kg = key16 + (size_t)g * NPG;
  const float w10 = w1[0], w11 = w1[1], w12 = w1[2], w13 = w1[3], w14 = w1[4];

  for (int rep = 0; rep < R; ++rep) {
    for (int i = tid; i < 16 * 264; i += 1024) whist[i] = 0;
    if (tid == 0) { s_cnt = 0; s_rem = K1; s_nc = 0; s_prefix = 0u; }
    __syncthreads();

    // per-wave 256-bin histogram of key16>>8 (dense reads, no cross-wave contention)
    {
      uint32_t* wh = whist + wid * 264;
#pragma unroll
      for (int q = 0; q < 8; ++q) {
        uint2 pk = ((const uint2*)kg)[tid + 1024 * q];
        atomicAdd(&wh[(pk.x >> 8) & 0xFFu], 1u);
        atomicAdd(&wh[(pk.x >> 24)], 1u);
        atomicAdd(&wh[(pk.y >> 8) & 0xFFu], 1u);
        atomicAdd(&wh[(pk.y >> 24)], 1u);
      }
    }
    __syncthreads();
    if (tid < 256) {
      uint32_t s = 0;
#pragma unroll
      for (int w = 0; w < 16; ++w) s += whist[w * 264 + tid];
      hist256[tid] = s;
    }
    __syncthreads();

    pick_bucket(hist256, 256, 8, &s_prefix, &s_rem, &s_nc, tid);
    __syncthreads();
    int consumed = 8;
    if (s_nc > 1024) {
      const uint32_t pref8 = s_prefix;
      __syncthreads();
      if (tid < 256) hist256[tid] = 0;
      __syncthreads();
#pragma unroll
      for (int q = 0; q < 8; ++q) {
        uint2 pk = ((const uint2*)kg)[tid + 1024 * q];
        uint32_t h0 = pk.x & 0xFFFFu, h1 = pk.x >> 16;
        uint32_t h2 = pk.y & 0xFFFFu, h3 = pk.y >> 16;
        if ((h0 >> 8) == pref8) atomicAdd(&hist256[h0 & 255u], 1u);
        if ((h1 >> 8) == pref8) atomicAdd(&hist256[h1 & 255u], 1u);
        if ((h2 >> 8) == pref8) atomicAdd(&hist256[h2 & 255u], 1u);
        if ((h3 >> 8) == pref8) atomicAdd(&hist256[h3 & 255u], 1u);
      }
      __syncthreads();
      pick_bucket(hist256, 256, 8, &s_prefix, &s_rem, &s_nc, tid);
      __syncthreads();
      consumed = 16;
    }
    const uint32_t T16 = s_prefix << (16 - consumed);  // monotone-trunc superset

    // collect candidates; recompute EXACT dot
    for (int q = 0; q < 8; ++q) {
      const int g4 = tid + 1024 * q;
      uint2 pk = ((const uint2*)kg)[g4];
      uint32_t h[4] = { pk.x & 0xFFFFu, pk.x >> 16, pk.y & 0xFFFFu, pk.y >> 16 };
#pragma unroll
      for (int j = 0; j < 4; ++j) {
        if (h[j] >= T16) {
          int p = atomicAdd(&s_cnt, 1);
          if (p < 1024) {
            int i = 4 * g4 + j;
            const float* r = xg + (size_t)i * L1;
            float dv = r[0]*w10 + r[1]*w11 + r[2]*w12 + r[3]*w13 + r[4]*w14;
            comp[p] = ((unsigned long long)mono(dv) << 16) | (unsigned)(65535 - i);
          }
        }
      }
    }
    __syncthreads();
    int cnt = s_cnt; if (cnt > 1024) cnt = 1024;
    const int nrk = (cnt <= 512) ? 512 : 1024;
    for (int i = tid; i < nrk; i += 1024)
      if (i >= cnt) comp[i] = 0ULL;
    __syncthreads();
    if (tid < nrk) {   // unrolled broadcast counting-rank
      unsigned long long c = comp[tid];
      int r = 0;
      for (int i = 0; i < nrk; i += 8) {
        ulonglong2 v0 = *(const ulonglong2*)&comp[i];
        ulonglong2 v1 = *(const ulonglong2*)&comp[i + 2];
        ulonglong2 v2 = *(const ulonglong2*)&comp[i + 4];
        ulonglong2 v3 = *(const ulonglong2*)&comp[i + 6];
        r += (v0.x > c) + (v0.y > c) + (v1.x > c) + (v1.y > c) +
             (v2.x > c) + (v2.y > c) + (v3.x > c) + (v3.y > c);
      }
      if (r < K1) sorted[r] = c;
    }
    __syncthreads();
    for (int j = tid; j < K1; j += 1024) selg[(size_t)g * 512 + j] = sorted[j];
    __syncthreads();   // WAR before next rep
  }
}

// ---- kernel 3: MLP phases E..J only ----
__global__ __launch_bounds__(1024, 1) void mlp_kernel(
    const float* __restrict__ x, const unsigned long long* __restrict__ selg,
    const float* __restrict__ w1, const float* __restrict__ W_ih,
    const float* __restrict__ b_ih, const float* __restrict__ b_hh,
    const float* __restrict__ w2, const float* __restrict__ W2,
    const float* __restrict__ b2, const float* __restrict__ w3,
    const float* __restrict__ W3, const float* __restrict__ b3,
    float* __restrict__ out, int R) {
  __shared__ __align__(16) float hbuf[K1 * 65 + K2 * 65 + K2 * 33];  // 98.2 KB
  __shared__ __align__(16) unsigned long long comp[512];
  __shared__ __align__(16) unsigned long long sorted[512];
  __shared__ __align__(16) float fa[4608];
  __shared__ float s_inv[3];

  float* xsel = fa;                  // [K1*L1]
  float* sWih = fa + 1640;
  float* sbih = fa + 1960;           // b_ih + b_hh
  float* sW2  = fa + 2024;           // [L3][65]
  float* sb2  = fa + 4104;
  float* sw2v = fa + 4136;
  float* sw3v = fa + 4200;
  float* sW3  = fa + 4232;
  float* sb3  = fa + 4488;

  const int tid = threadIdx.x;
  const int g = blockIdx.x;
  const float* xg = x + (size_t)g * NPG * L1;

  for (int rep = 0; rep < R; ++rep) {
    for (int i = tid; i < L2 * L1; i += 1024) sWih[i] = W_ih[i];
    for (int i = tid; i < L2; i += 1024) { sbih[i] = b_ih[i] + b_hh[i]; sw2v[i] = w2[i]; }
    for (int i = tid; i < L3 * L2; i += 1024) sW2[(i >> 6) * 65 + (i & 63)] = W2[i];
    for (int i = tid; i < L3; i += 1024) { sb2[i] = b2[i]; sw3v[i] = w3[i]; }
    for (int i = tid; i < L4 * L3; i += 1024) sW3[i] = W3[i];
    for (int i = tid; i < L4; i += 1024) sb3[i] = b3[i];
    if (tid < 64) {   // parallel norms (replaces serial tid==0/1/2 loops)
      float a = (tid < L1) ? w1[tid] : 0.f;
      float b = w2[tid];
      float c = (tid < L3) ? w3[tid] : 0.f;
      a *= a; b *= b; c *= c;
      for (int d = 1; d < 64; d <<= 1) {
        a += __shfl_xor(a, d); b += __shfl_xor(b, d); c += __shfl_xor(c, d);
      }
      if (tid == 0) {
        s_inv[0] = 1.f / sqrtf(a); s_inv[1] = 1.f / sqrtf(b); s_inv[2] = 1.f / sqrtf(c);
      }
    }
    for (int j = tid; j < K1; j += 1024) sorted[j] = selg[(size_t)g * 512 + j];
    __syncthreads();

    const float inv1 = s_inv[0], inv2 = s_inv[1], inv3 = s_inv[2];

    // phase E: gather x rows * score1
    for (int p = tid; p < K1 * L1; p += 1024) {
      int j = p / L1, k = p - j * L1;
      unsigned long long c = sorted[j];
      int idx = 65535 - (int)(c & 0xFFFFu);
      float sc = tanhf(imono((uint32_t)(c >> 16)) * inv1);
      xsel[p] = xg[(size_t)idx * L1 + k] * sc;
    }
    __syncthreads();
    // RNNCell -> h[328][65-stride]
    for (int p = tid; p < K1 * L2; p += 1024) {
      int row = p >> 6, o = p & 63;
      const float* wr = sWih + o * L1;
      const float* xr = xsel + row * L1;
      float acc = sbih[o];
#pragma unroll
      for (int k = 0; k < L1; ++k) acc += xr[k] * wr[k];
      hbuf[row * 65 + o] = tanhf(acc);
    }
    __syncthreads();

    // pool2: scores -> comp[0..512), counting-rank -> sorted
    for (int j = tid; j < 512; j += 1024) {
      unsigned long long c = 0ULL;
      if (j < K1) {
        const float* hr = hbuf + j * 65;
        float acc = 0.f;
        for (int k = 0; k < L2; ++k) acc += hr[k] * sw2v[k];
        c = ((unsigned long long)mono(acc) << 16) | (unsigned)(65535 - j);
      }
      comp[j] = c;
    }
    __syncthreads();
    if (tid < 512) {
      unsigned long long c = comp[tid];
      int r = 0;
      for (int i = 0; i < 512; i += 8) {
        ulonglong2 v0 = *(const ulonglong2*)&comp[i];
        ulonglong2 v1 = *(const ulonglong2*)&comp[i + 2];
        ulonglong2 v2 = *(const ulonglong2*)&comp[i + 4];
        ulonglong2 v3 = *(const ulonglong2*)&comp[i + 6];
        r += (v0.x > c) + (v0.y > c) + (v1.x > c) + (v1.y > c) +
             (v2.x > c) + (v2.y > c) + (v3.x > c) + (v3.y > c);
      }
      sorted[r] = c;
    }
    __syncthreads();

    // phase G: x2[33][65] = h[sel] * score2
    float* x2f = hbuf + K1 * 65;
    for (int p = tid; p < K2 * L2; p += 1024) {
      int j = p >> 6, k = p & 63;
      unsigned long long c = sorted[j];
      int row = 65535 - (int)(c & 0xFFFFu);
      float sc = tanhf(imono((uint32_t)(c >> 16)) * inv2);
      x2f[j * 65 + k] = hbuf[row * 65 + k] * sc;
    }
    __syncthreads();

    // phase H: y[33][32] = relu(x2 @ W2^T + b2)
    float* yf = x2f + K2 * 65;  // stride 33
    for (int p = tid; p < K2 * L3; p += 1024) {
      int j = p >> 5, o = p & 31;
      const float* xr = x2f + j * 65;
      const float* wr = sW2 + o * 65;
      float acc = sb2[o];
      for (int k = 0; k < L2; ++k) acc += xr[k] * wr[k];
      yf[j * 33 + o] = fmaxf(acc, 0.f);
    }
    __syncthreads();

    // pool3: scores -> comp[0..64), counting-rank(64) -> sorted
    for (int j = tid; j < 64; j += 1024) {
      unsigned long long c = 0ULL;
      if (j < K2) {
        const float* yr = yf + j * 33;
        float acc = 0.f;
        for (int k = 0; k < L3; ++k) acc += yr[k] * sw3v[k];
        c = ((unsigned long long)mono(acc) << 16) | (unsigned)(65535 - j);
      }
      comp[j] = c;
    }
    __syncthreads();
    if (tid < 64) {
      unsigned long long c = comp[tid];
      int r = 0;
      for (int i = 0; i < 64; i += 8) {
        ulonglong2 v0 = *(const ulonglong2*)&comp[i];
        ulonglong2 v1 = *(const ulonglong2*)&comp[i + 2];
        ulonglong2 v2 = *(const ulonglong2*)&comp[i + 4];
        ulonglong2 v3 = *(const ulonglong2*)&comp[i + 6];
        r += (v0.x > c) + (v0.y > c) + (v1.x > c) + (v1.y > c) +
             (v2.x > c) + (v2.y > c) + (v3.x > c) + (v3.y > c);
      }
      sorted[r] = c;
    }
    __syncthreads();

    // phase J: out[4][8] = (y[sel]*score3) @ W3^T + b3
    for (int p = tid; p < K3 * L4; p += 1024) {
      int t = p >> 3, o = p & 7;
      unsigned long long c = sorted[t];
      int row = 65535 - (int)(c & 0xFFFFu);
      float sc = tanhf(imono((uint32_t)(c >> 16)) * inv3);
      const float* yr = yf + row * 33;
      const float* wr = sW3 + o * L3;
      float acc = sb3[o];
      for (int k = 0; k < L3; ++k) acc += yr[k] * sc * wr[k];
      out[((size_t)g * K3 + t) * L4 + o] = acc;
    }
    __syncthreads();   // WAR before next rep
  }
}

extern "C" void kernel_launch(void* const* d_in, const int* in_sizes, int n_in,
                              void* d_out, int out_size, void* d_ws, size_t ws_size,
                              hipStream_t stream) {
  const float* x    = (const float*)d_in[0];
  // d_in[1] = edge_index (unused), d_in[2] = batch (unused: static contiguous grouping)
  const float* w1   = (const float*)d_in[3];
  const float* W_ih = (const float*)d_in[4];
  const float* b_ih = (const float*)d_in[5];
  const float* b_hh = (const float*)d_in[6];
  const float* w2   = (const float*)d_in[7];
  const float* W2   = (const float*)d_in[8];
  const float* b2   = (const float*)d_in[9];
  const float* w3   = (const float*)d_in[10];
  const float* W3   = (const float*)d_in[11];
  const float* b3   = (const float*)d_in[12];
  float* out = (float*)d_out;

  uint32_t* key32 = (uint32_t*)d_ws;                                   // 8 MB
  unsigned long long* selg =
      (unsigned long long*)((char*)d_ws + (size_t)NGRAPH * NPG * 2);   // 512 KB

  // DIAGNOSTIC ROUND: repeats make each phase >75 us so each gets its own
  // rocprof top-5 row (fills at ~75 us otherwise hide them). Per-phase time
  // = row dur / repeat. State is identical to R=1 (idempotent phases).
  score_kernel<<<dim3(NGRAPH * 16), dim3(256), 0, stream>>>(x, w1, key32, R_SCORE);
  select_kernel<<<dim3(NGRAPH), dim3(1024), 0, stream>>>(
      x, (const uint16_t*)key32, w1, selg, R_SEL);
  mlp_kernel<<<dim3(NGRAPH), dim3(1024), 0, stream>>>(
      x, selg, w1, W_ih, b_ih, b_hh, w2, W2, b2, w3, W3, b3, out, R_MLP);
}

// Round 10
// 86.127 us; speedup vs baseline: 19.3044x; 19.3044x over previous
//
#include <hip/hip_runtime.h>
#include <stdint.h>
#include <math.h>

constexpr int NPG = 32768;
constexpr int NGRAPH = 128;
constexpr int L1 = 5, L2 = 64, L3 = 32, L4 = 8;
constexpr int K1 = 328, K2 = 33, K3 = 4;

__device__ __forceinline__ uint32_t mono(float f) {
  uint32_t u = __float_as_uint(f);
  return (u & 0x80000000u) ? ~u : (u | 0x80000000u);
}
__device__ __forceinline__ float imono(uint32_t k) {
  uint32_t u = (k & 0x80000000u) ? (k ^ 0x80000000u) : ~k;
  return __uint_as_float(u);
}
// robust fast tanh: 1 - 2/(e^{2x}+1); exact at +/-inf, ~1e-6 rel err (budget 3e-3)
__device__ __forceinline__ float fast_tanh(float x) {
  float e = __expf(2.0f * x);
  return 1.0f - 2.0f / (e + 1.0f);
}

// ---- kernel 1: DENSE score stream (r8-identical math) ----
__global__ __launch_bounds__(256) void score_kernel(
    const float* __restrict__ x, const float* __restrict__ w1,
    uint32_t* __restrict__ key32) {
  __shared__ __align__(16) float sb[2048 * L1];   // 40 KB
  const int tid = threadIdx.x;
  const int g = blockIdx.x >> 4;
  const int bg = blockIdx.x & 15;
  const float w10 = w1[0], w11 = w1[1], w12 = w1[2], w13 = w1[3], w14 = w1[4];
  const float4* src = (const float4*)(x + ((size_t)g * NPG + bg * 2048) * L1);
#pragma unroll
  for (int k = 0; k < 10; ++k)
    ((float4*)sb)[tid + 256 * k] = src[tid + 256 * k];
  __syncthreads();
  uint32_t* kg = key32 + (size_t)g * (NPG / 2) + bg * 1024;
#pragma unroll
  for (int p = 0; p < 4; ++p) {
    const int np = tid + 256 * p;                 // node pair: word np = nodes 2np,2np+1
    const float* r = sb + np * 10;
    float d0 = r[0]*w10 + r[1]*w11 + r[2]*w12 + r[3]*w13 + r[4]*w14;
    float d1 = r[5]*w10 + r[6]*w11 + r[7]*w12 + r[8]*w13 + r[9]*w14;
    kg[np] = (mono(d0) >> 16) | (mono(d1) & 0xFFFF0000u);
  }
}

// ---- kernel 2: histogram-free select (register keys + sample + exact count) + MLP ----
__global__ __launch_bounds__(1024, 1) void selmlp_kernel(
    const float* __restrict__ x, const uint32_t* __restrict__ key32,
    const float* __restrict__ w1, const float* __restrict__ W_ih,
    const float* __restrict__ b_ih, const float* __restrict__ b_hh,
    const float* __restrict__ w2, const float* __restrict__ W2,
    const float* __restrict__ b2, const float* __restrict__ w3,
    const float* __restrict__ W3, const float* __restrict__ b3,
    float* __restrict__ out) {
  __shared__ __align__(16) float hbuf[K1 * 65 + K2 * 65 + K2 * 33];  // 98.2 KB
  __shared__ __align__(16) unsigned long long comp[1024];   // 8 KB
  __shared__ __align__(16) unsigned long long sorted[512];  // 4 KB
  __shared__ __align__(16) float fa[4608];                  // 18 KB
  __shared__ __align__(16) uint32_t samp[256];              // 1 KB
  __shared__ uint32_t s_T5[5];
  __shared__ int wred[16 * 5];
  __shared__ int s_lo, s_hi, s_done, s_cnt;
  __shared__ uint32_t s_T16;
  __shared__ float s_inv[3];

  float* xsel = fa;                  // [K1*L1]
  float* sWih = fa + 1640;
  float* sbih = fa + 1960;           // b_ih + b_hh
  float* sW2  = fa + 2024;           // [L3][65]
  float* sb2  = fa + 4104;
  float* sw2v = fa + 4136;
  float* sw3v = fa + 4200;
  float* sW3  = fa + 4232;
  float* sb3  = fa + 4488;

  const int tid = threadIdx.x;
  const int wid = tid >> 6;
  const int g = blockIdx.x;
  const float* xg = x + (size_t)g * NPG * L1;
  const uint4* k4 = (const uint4*)(key32 + (size_t)g * (NPG / 2));

  // 32 keys per thread in registers; uint4 V covers nodes 8V..8V+7
  uint4 kr[4];
#pragma unroll
  for (int q = 0; q < 4; ++q) kr[q] = k4[q * 1024 + tid];   // coalesced

  // stage weights + norms
  for (int i = tid; i < L2 * L1; i += 1024) sWih[i] = W_ih[i];
  for (int i = tid; i < L2; i += 1024) { sbih[i] = b_ih[i] + b_hh[i]; sw2v[i] = w2[i]; }
  for (int i = tid; i < L3 * L2; i += 1024) sW2[(i >> 6) * 65 + (i & 63)] = W2[i];
  for (int i = tid; i < L3; i += 1024) { sb2[i] = b2[i]; sw3v[i] = w3[i]; }
  for (int i = tid; i < L4 * L3; i += 1024) sW3[i] = W3[i];
  for (int i = tid; i < L4; i += 1024) sb3[i] = b3[i];
  if (tid < 64) {
    float a = (tid < L1) ? w1[tid] : 0.f;
    float b = w2[tid];
    float c = (tid < L3) ? w3[tid] : 0.f;
    a *= a; b *= b; c *= c;
    for (int d = 1; d < 64; d <<= 1) {
      a += __shfl_xor(a, d); b += __shfl_xor(b, d); c += __shfl_xor(c, d);
    }
    if (tid == 0) {
      s_inv[0] = 1.f / sqrtf(a); s_inv[1] = 1.f / sqrtf(b); s_inv[2] = 1.f / sqrtf(c);
      s_cnt = 0; s_done = 0; s_lo = 0; s_hi = 65536;
    }
  }
  // distinct samples: (key16<<8)|tid, sample node = 8*tid
  if (tid < 256) samp[tid] = ((kr[0].x & 0xFFFFu) << 8) | (uint32_t)tid;
  __syncthreads();

  // rank 256 distinct samples by broadcast scan; publish 5 quantile thresholds
  if (tid < 256) {
    const uint32_t s = samp[tid];
    int r = 0;
    for (int i = 0; i < 64; ++i) {
      uint4 v = ((const uint4*)samp)[i];
      r += (v.x > s) + (v.y > s) + (v.z > s) + (v.w > s);
    }
    uint32_t key = s >> 8;
    if (r == 3)  s_T5[0] = key;
    if (r == 5)  s_T5[1] = key;
    if (r == 7)  s_T5[2] = key;
    if (r == 10) s_T5[3] = key;
    if (r == 14) s_T5[4] = key;
  }
  __syncthreads();

  // one atomic-free pass: exact counts for all 5 thresholds
  {
    uint32_t T0 = s_T5[0], T1 = s_T5[1], T2 = s_T5[2], T3 = s_T5[3], T4 = s_T5[4];
    int c0 = 0, c1 = 0, c2 = 0, c3 = 0, c4 = 0;
#pragma unroll
    for (int q = 0; q < 4; ++q) {
      uint32_t w[4] = { kr[q].x, kr[q].y, kr[q].z, kr[q].w };
#pragma unroll
      for (int j = 0; j < 4; ++j) {
        uint32_t lo = w[j] & 0xFFFFu, hi = w[j] >> 16;
        c0 += (lo >= T0) + (hi >= T0); c1 += (lo >= T1) + (hi >= T1);
        c2 += (lo >= T2) + (hi >= T2); c3 += (lo >= T3) + (hi >= T3);
        c4 += (lo >= T4) + (hi >= T4);
      }
    }
    for (int d = 1; d < 64; d <<= 1) {
      c0 += __shfl_xor(c0, d); c1 += __shfl_xor(c1, d); c2 += __shfl_xor(c2, d);
      c3 += __shfl_xor(c3, d); c4 += __shfl_xor(c4, d);
    }
    if ((tid & 63) == 0) {
      wred[wid * 5 + 0] = c0; wred[wid * 5 + 1] = c1; wred[wid * 5 + 2] = c2;
      wred[wid * 5 + 3] = c3; wred[wid * 5 + 4] = c4;
    }
  }
  __syncthreads();
  if (tid == 0) {
    int tot[5] = {0, 0, 0, 0, 0};
    for (int w = 0; w < 16; ++w)
      for (int j = 0; j < 5; ++j) tot[j] += wred[w * 5 + j];
    // counts ascend with j (thresholds descend). pick first j with tot in range.
    int done = 0;
    for (int j = 0; j < 5 && !done; ++j)
      if (tot[j] >= K1 && tot[j] <= 1024) { s_T16 = s_T5[j]; done = 1; }
    if (!done) {  // brackets for binary search: lo=count>1024 side, hi=count<328 side
      int lo = 0, hi = 65536;
      for (int j = 0; j < 5; ++j) {
        if (tot[j] > 1024) { lo = (int)s_T5[j]; break; }       // largest such T
      }
      for (int j = 4; j >= 0; --j) {
        if (tot[j] < K1) { hi = (int)s_T5[j]; break; }         // smallest such T
      }
      s_lo = lo; s_hi = hi;
    }
    s_done = done;
  }
  __syncthreads();

  // exact binary search fallback (rare): one register count pass per iter
  for (int it = 0; it < 16; ++it) {
    if (s_done) break;                       // uniform (shared)
    const uint32_t q = (uint32_t)((s_lo + s_hi) >> 1);
    int cc = 0;
#pragma unroll
    for (int qq = 0; qq < 4; ++qq) {
      uint32_t w[4] = { kr[qq].x, kr[qq].y, kr[qq].z, kr[qq].w };
#pragma unroll
      for (int j = 0; j < 4; ++j) {
        cc += ((w[j] & 0xFFFFu) >= q) + ((w[j] >> 16) >= q);
      }
    }
    for (int d = 1; d < 64; d <<= 1) cc += __shfl_xor(cc, d);
    if ((tid & 63) == 0) wred[wid] = cc;
    __syncthreads();
    if (tid == 0) {
      int tot = 0;
      for (int w = 0; w < 16; ++w) tot += wred[w];
      if (tot >= K1 && tot <= 1024) { s_T16 = q; s_done = 1; }
      else if (s_hi - s_lo <= 1)    { s_T16 = (uint32_t)s_lo; s_done = 1; } // plateau cap
      else if (tot > 1024)          { s_lo = (int)q; }
      else                          { s_hi = (int)q; }
    }
    __syncthreads();
  }
  const uint32_t T16 = s_T16;
  const float w10 = w1[0], w11 = w1[1], w12 = w1[2], w13 = w1[3], w14 = w1[4];

  // collect candidates from register keys; recompute EXACT dot
#pragma unroll
  for (int q = 0; q < 4; ++q) {
    const int nb = 8 * (q * 1024 + tid);
    uint32_t w[4] = { kr[q].x, kr[q].y, kr[q].z, kr[q].w };
#pragma unroll
    for (int j = 0; j < 4; ++j) {
      uint32_t lo = w[j] & 0xFFFFu, hi = w[j] >> 16;
      if (lo >= T16) {
        int p = atomicAdd(&s_cnt, 1);
        if (p < 1024) {
          int i = nb + 2 * j;
          const float* r = xg + (size_t)i * L1;
          float dv = r[0]*w10 + r[1]*w11 + r[2]*w12 + r[3]*w13 + r[4]*w14;
          comp[p] = ((unsigned long long)mono(dv) << 16) | (unsigned)(65535 - i);
        }
      }
      if (hi >= T16) {
        int p = atomicAdd(&s_cnt, 1);
        if (p < 1024) {
          int i = nb + 2 * j + 1;
          const float* r = xg + (size_t)i * L1;
          float dv = r[0]*w10 + r[1]*w11 + r[2]*w12 + r[3]*w13 + r[4]*w14;
          comp[p] = ((unsigned long long)mono(dv) << 16) | (unsigned)(65535 - i);
        }
      }
    }
  }
  __syncthreads();
  int cnt = s_cnt; if (cnt > 1024) cnt = 1024;
  const int nrk = (cnt <= 512) ? 512 : 1024;
  for (int i = tid; i < nrk; i += 1024)
    if (i >= cnt) comp[i] = 0ULL;
  __syncthreads();
  if (tid < nrk) {   // unrolled broadcast counting-rank
    unsigned long long c = comp[tid];
    int r = 0;
    for (int i = 0; i < nrk; i += 8) {
      ulonglong2 v0 = *(const ulonglong2*)&comp[i];
      ulonglong2 v1 = *(const ulonglong2*)&comp[i + 2];
      ulonglong2 v2 = *(const ulonglong2*)&comp[i + 4];
      ulonglong2 v3 = *(const ulonglong2*)&comp[i + 6];
      r += (v0.x > c) + (v0.y > c) + (v1.x > c) + (v1.y > c) +
           (v2.x > c) + (v2.y > c) + (v3.x > c) + (v3.y > c);
    }
    if (r < K1) sorted[r] = c;
  }
  __syncthreads();

  const float inv1 = s_inv[0], inv2 = s_inv[1], inv3 = s_inv[2];

  // phase E: gather x rows * score1
  for (int p = tid; p < K1 * L1; p += 1024) {
    int j = p / L1, k = p - j * L1;
    unsigned long long c = sorted[j];
    int idx = 65535 - (int)(c & 0xFFFFu);
    float sc = fast_tanh(imono((uint32_t)(c >> 16)) * inv1);
    xsel[p] = xg[(size_t)idx * L1 + k] * sc;
  }
  __syncthreads();
  // RNNCell -> h[328][65-stride]
  for (int p = tid; p < K1 * L2; p += 1024) {
    int row = p >> 6, o = p & 63;
    const float* wr = sWih + o * L1;
    const float* xr = xsel + row * L1;
    float acc = sbih[o];
#pragma unroll
    for (int k = 0; k < L1; ++k) acc += xr[k] * wr[k];
    hbuf[row * 65 + o] = fast_tanh(acc);
  }
  __syncthreads();

  // pool2: scores -> comp[0..512), counting-rank -> sorted
  for (int j = tid; j < 512; j += 1024) {
    unsigned long long c = 0ULL;
    if (j < K1) {
      const float* hr = hbuf + j * 65;
      float acc = 0.f;
      for (int k = 0; k < L2; ++k) acc += hr[k] * sw2v[k];
      c = ((unsigned long long)mono(acc) << 16) | (unsigned)(65535 - j);
    }
    comp[j] = c;
  }
  __syncthreads();
  if (tid < 512) {
    unsigned long long c = comp[tid];
    int r = 0;
    for (int i = 0; i < 512; i += 8) {
      ulonglong2 v0 = *(const ulonglong2*)&comp[i];
      ulonglong2 v1 = *(const ulonglong2*)&comp[i + 2];
      ulonglong2 v2 = *(const ulonglong2*)&comp[i + 4];
      ulonglong2 v3 = *(const ulonglong2*)&comp[i + 6];
      r += (v0.x > c) + (v0.y > c) + (v1.x > c) + (v1.y > c) +
           (v2.x > c) + (v2.y > c) + (v3.x > c) + (v3.y > c);
    }
    sorted[r] = c;
  }
  __syncthreads();

  // phase G: x2[33][65] = h[sel] * score2
  float* x2f = hbuf + K1 * 65;
  for (int p = tid; p < K2 * L2; p += 1024) {
    int j = p >> 6, k = p & 63;
    unsigned long long c = sorted[j];
    int row = 65535 - (int)(c & 0xFFFFu);
    float sc = fast_tanh(imono((uint32_t)(c >> 16)) * inv2);
    x2f[j * 65 + k] = hbuf[row * 65 + k] * sc;
  }
  __syncthreads();

  // phase H: y[33][32] = relu(x2 @ W2^T + b2)
  float* yf = x2f + K2 * 65;  // stride 33
  for (int p = tid; p < K2 * L3; p += 1024) {
    int j = p >> 5, o = p & 31;
    const float* xr = x2f + j * 65;
    const float* wr = sW2 + o * 65;
    float acc = sb2[o];
    for (int k = 0; k < L2; ++k) acc += xr[k] * wr[k];
    yf[j * 33 + o] = fmaxf(acc, 0.f);
  }
  __syncthreads();

  // pool3: scores -> comp[0..64), counting-rank(64) -> sorted
  for (int j = tid; j < 64; j += 1024) {
    unsigned long long c = 0ULL;
    if (j < K2) {
      const float* yr = yf + j * 33;
      float acc = 0.f;
      for (int k = 0; k < L3; ++k) acc += yr[k] * sw3v[k];
      c = ((unsigned long long)mono(acc) << 16) | (unsigned)(65535 - j);
    }
    comp[j] = c;
  }
  __syncthreads();
  if (tid < 64) {
    unsigned long long c = comp[tid];
    int r = 0;
    for (int i = 0; i < 64; i += 8) {
      ulonglong2 v0 = *(const ulonglong2*)&comp[i];
      ulonglong2 v1 = *(const ulonglong2*)&comp[i + 2];
      ulonglong2 v2 = *(const ulonglong2*)&comp[i + 4];
      ulonglong2 v3 = *(const ulonglong2*)&comp[i + 6];
      r += (v0.x > c) + (v0.y > c) + (v1.x > c) + (v1.y > c) +
           (v2.x > c) + (v2.y > c) + (v3.x > c) + (v3.y > c);
    }
    sorted[r] = c;
  }
  __syncthreads();

  // phase J: out[4][8] = (y[sel]*score3) @ W3^T + b3
  for (int p = tid; p < K3 * L4; p += 1024) {
    int t = p >> 3, o = p & 7;
    unsigned long long c = sorted[t];
    int row = 65535 - (int)(c & 0xFFFFu);
    float sc = fast_tanh(imono((uint32_t)(c >> 16)) * inv3);
    const float* yr = yf + row * 33;
    const float* wr = sW3 + o * L3;
    float acc = sb3[o];
    for (int k = 0; k < L3; ++k) acc += yr[k] * sc * wr[k];
    out[((size_t)g * K3 + t) * L4 + o] = acc;
  }
}

extern "C" void kernel_launch(void* const* d_in, const int* in_sizes, int n_in,
                              void* d_out, int out_size, void* d_ws, size_t ws_size,
                              hipStream_t stream) {
  const float* x    = (const float*)d_in[0];
  // d_in[1] = edge_index (unused), d_in[2] = batch (unused: static contiguous grouping)
  const float* w1   = (const float*)d_in[3];
  const float* W_ih = (const float*)d_in[4];
  const float* b_ih = (const float*)d_in[5];
  const float* b_hh = (const float*)d_in[6];
  const float* w2   = (const float*)d_in[7];
  const float* W2   = (const float*)d_in[8];
  const float* b2   = (const float*)d_in[9];
  const float* w3   = (const float*)d_in[10];
  const float* W3   = (const float*)d_in[11];
  const float* b3   = (const float*)d_in[12];
  float* out = (float*)d_out;

  uint32_t* key32 = (uint32_t*)d_ws;   // 8 MB packed key16

  score_kernel<<<dim3(NGRAPH * 16), dim3(256), 0, stream>>>(x, w1, key32);
  selmlp_kernel<<<dim3(NGRAPH), dim3(1024), 0, stream>>>(
      x, key32, w1, W_ih, b_ih, b_hh, w2, W2, b2, w3, W3, b3, out);
}

// Round 11
// 80.217 us; speedup vs baseline: 20.7267x; 1.0737x over previous
//
#include <hip/hip_runtime.h>
#include <stdint.h>
#include <math.h>

constexpr int NPG = 32768;
constexpr int NGRAPH = 128;
constexpr int L1 = 5, L2 = 64, L3 = 32, L4 = 8;
constexpr int K1 = 328, K2 = 33, K3 = 4;

__device__ __forceinline__ uint32_t mono(float f) {
  uint32_t u = __float_as_uint(f);
  return (u & 0x80000000u) ? ~u : (u | 0x80000000u);
}
__device__ __forceinline__ float imono(uint32_t k) {
  uint32_t u = (k & 0x80000000u) ? (k ^ 0x80000000u) : ~k;
  return __uint_as_float(u);
}
// robust fast tanh: 1 - 2/(e^{2x}+1); exact at +/-inf, ~1e-6 rel err (budget 3e-3)
__device__ __forceinline__ float fast_tanh(float x) {
  float e = __expf(2.0f * x);
  return 1.0f - 2.0f / (e + 1.0f);
}

// ---- kernel 1: DENSE score stream (r8-identical) ----
__global__ __launch_bounds__(256) void score_kernel(
    const float* __restrict__ x, const float* __restrict__ w1,
    uint32_t* __restrict__ key32) {
  __shared__ __align__(16) float sb[2048 * L1];   // 40 KB
  const int tid = threadIdx.x;
  const int g = blockIdx.x >> 4;
  const int bg = blockIdx.x & 15;
  const float w10 = w1[0], w11 = w1[1], w12 = w1[2], w13 = w1[3], w14 = w1[4];
  const float4* src = (const float4*)(x + ((size_t)g * NPG + bg * 2048) * L1);
#pragma unroll
  for (int k = 0; k < 10; ++k)
    ((float4*)sb)[tid + 256 * k] = src[tid + 256 * k];
  __syncthreads();
  uint32_t* kg = key32 + (size_t)g * (NPG / 2) + bg * 1024;
#pragma unroll
  for (int p = 0; p < 4; ++p) {
    const int np = tid + 256 * p;                 // word np = nodes 2np (lo16), 2np+1 (hi16)
    const float* r = sb + np * 10;
    float d0 = r[0]*w10 + r[1]*w11 + r[2]*w12 + r[3]*w13 + r[4]*w14;
    float d1 = r[5]*w10 + r[6]*w11 + r[7]*w12 + r[8]*w13 + r[9]*w14;
    kg[np] = (mono(d0) >> 16) | (mono(d1) & 0xFFFF0000u);
  }
}

// ---- kernel 2: sampling select (no histograms, no LDS atomics) + MLP ----
__global__ __launch_bounds__(1024, 1) void selmlp_kernel(
    const float* __restrict__ x, const uint32_t* __restrict__ key32,
    const float* __restrict__ w1, const float* __restrict__ W_ih,
    const float* __restrict__ b_ih, const float* __restrict__ b_hh,
    const float* __restrict__ w2, const float* __restrict__ W2,
    const float* __restrict__ b2, const float* __restrict__ w3,
    const float* __restrict__ W3, const float* __restrict__ b3,
    float* __restrict__ out) {
  __shared__ __align__(16) float hbuf[K1 * 65 + K2 * 65 + K2 * 33];  // 98.2 KB
  __shared__ __align__(16) unsigned long long comp[1024];   // 8 KB
  __shared__ __align__(16) unsigned long long sorted[512];  // 4 KB
  __shared__ __align__(16) float fa[4608];                  // 18 KB
  __shared__ __align__(16) uint32_t samp[512];              // 2 KB
  __shared__ uint32_t s_T5[5];
  __shared__ int wred[16 * 5];
  __shared__ int s_lo, s_hi, s_done, s_cnt;
  __shared__ uint32_t s_T16;
  __shared__ float s_inv[3];

  float* xsel = fa;                  // [K1*L1]
  float* sWih = fa + 1640;
  float* sbih = fa + 1960;           // b_ih + b_hh
  float* sW2  = fa + 2024;           // [L3][65]
  float* sb2  = fa + 4104;
  float* sw2v = fa + 4136;
  float* sw3v = fa + 4200;
  float* sW3  = fa + 4232;
  float* sb3  = fa + 4488;

  const int tid = threadIdx.x;
  const int wid = tid >> 6;
  const int g = blockIdx.x;
  const float* xg = x + (size_t)g * NPG * L1;
  const uint4* k4 = (const uint4*)(key32 + (size_t)g * (NPG / 2));

  // 32 keys per thread in registers; uint4 V covers nodes 8V..8V+7
  uint4 kr[4];
#pragma unroll
  for (int q = 0; q < 4; ++q) kr[q] = k4[q * 1024 + tid];   // coalesced

  // stage weights + norms (overlaps key loads)
  for (int i = tid; i < L2 * L1; i += 1024) sWih[i] = W_ih[i];
  for (int i = tid; i < L2; i += 1024) { sbih[i] = b_ih[i] + b_hh[i]; sw2v[i] = w2[i]; }
  for (int i = tid; i < L3 * L2; i += 1024) sW2[(i >> 6) * 65 + (i & 63)] = W2[i];
  for (int i = tid; i < L3; i += 1024) { sb2[i] = b2[i]; sw3v[i] = w3[i]; }
  for (int i = tid; i < L4 * L3; i += 1024) sW3[i] = W3[i];
  for (int i = tid; i < L4; i += 1024) sb3[i] = b3[i];
  if (tid < 64) {
    float a = (tid < L1) ? w1[tid] : 0.f;
    float b = w2[tid];
    float c = (tid < L3) ? w3[tid] : 0.f;
    a *= a; b *= b; c *= c;
    for (int d = 1; d < 64; d <<= 1) {
      a += __shfl_xor(a, d); b += __shfl_xor(b, d); c += __shfl_xor(c, d);
    }
    if (tid == 0) {
      s_inv[0] = 1.f / sqrtf(a); s_inv[1] = 1.f / sqrtf(b); s_inv[2] = 1.f / sqrtf(c);
      s_cnt = 0; s_done = 0; s_lo = 0; s_hi = 65536;
    }
  }
  // 512 distinct samples: (key16<<9)|tid, sample node = 8*tid
  if (tid < 512) samp[tid] = ((kr[0].x & 0xFFFFu) << 9) | (uint32_t)tid;
  __syncthreads();

  // rank 512 distinct samples by broadcast scan; thresholds at ranks 7/9/11/13/15
  if (tid < 512) {
    const uint32_t s = samp[tid];
    int r = 0;
    for (int i = 0; i < 128; ++i) {
      uint4 v = ((const uint4*)samp)[i];
      r += (v.x > s) + (v.y > s) + (v.z > s) + (v.w > s);
    }
    uint32_t key = s >> 9;
    if (r == 7)  s_T5[0] = key;
    if (r == 9)  s_T5[1] = key;
    if (r == 11) s_T5[2] = key;
    if (r == 13) s_T5[3] = key;
    if (r == 15) s_T5[4] = key;
  }
  __syncthreads();

  // one atomic-free register pass: exact counts for all 5 thresholds
  {
    uint32_t T0 = s_T5[0], T1 = s_T5[1], T2 = s_T5[2], T3 = s_T5[3], T4 = s_T5[4];
    int c0 = 0, c1 = 0, c2 = 0, c3 = 0, c4 = 0;
#pragma unroll
    for (int q = 0; q < 4; ++q) {
      uint32_t w[4] = { kr[q].x, kr[q].y, kr[q].z, kr[q].w };
#pragma unroll
      for (int j = 0; j < 4; ++j) {
        uint32_t lo = w[j] & 0xFFFFu, hi = w[j] >> 16;
        c0 += (lo >= T0) + (hi >= T0); c1 += (lo >= T1) + (hi >= T1);
        c2 += (lo >= T2) + (hi >= T2); c3 += (lo >= T3) + (hi >= T3);
        c4 += (lo >= T4) + (hi >= T4);
      }
    }
    for (int d = 1; d < 64; d <<= 1) {
      c0 += __shfl_xor(c0, d); c1 += __shfl_xor(c1, d); c2 += __shfl_xor(c2, d);
      c3 += __shfl_xor(c3, d); c4 += __shfl_xor(c4, d);
    }
    if ((tid & 63) == 0) {
      wred[wid * 5 + 0] = c0; wred[wid * 5 + 1] = c1; wred[wid * 5 + 2] = c2;
      wred[wid * 5 + 3] = c3; wred[wid * 5 + 4] = c4;
    }
  }
  __syncthreads();
  if (tid == 0) {
    int tot[5] = {0, 0, 0, 0, 0};
    for (int w = 0; w < 16; ++w)
      for (int j = 0; j < 5; ++j) tot[j] += wred[w * 5 + j];
    int done = 0;
    for (int j = 0; j < 5 && !done; ++j)
      if (tot[j] >= K1 && tot[j] <= 1024) { s_T16 = s_T5[j]; done = 1; }
    if (!done) {  // bracket the binary search with the sampled counts
      int lo = 0, hi = 65536;
      for (int j = 0; j < 5; ++j)
        if (tot[j] > 1024) { lo = (int)s_T5[j]; break; }
      for (int j = 4; j >= 0; --j)
        if (tot[j] < K1) { hi = (int)s_T5[j]; break; }
      s_lo = lo; s_hi = hi;
    }
    s_done = done;
  }
  __syncthreads();

  // exact binary search fallback (rare: ~0.3% of blocks)
  for (int it = 0; it < 16; ++it) {
    if (s_done) break;
    const uint32_t q = (uint32_t)((s_lo + s_hi) >> 1);
    int cc = 0;
#pragma unroll
    for (int qq = 0; qq < 4; ++qq) {
      uint32_t w[4] = { kr[qq].x, kr[qq].y, kr[qq].z, kr[qq].w };
#pragma unroll
      for (int j = 0; j < 4; ++j)
        cc += ((w[j] & 0xFFFFu) >= q) + ((w[j] >> 16) >= q);
    }
    for (int d = 1; d < 64; d <<= 1) cc += __shfl_xor(cc, d);
    if ((tid & 63) == 0) wred[wid] = cc;
    __syncthreads();
    if (tid == 0) {
      int tot = 0;
      for (int w = 0; w < 16; ++w) tot += wred[w];
      if (tot >= K1 && tot <= 1024) { s_T16 = q; s_done = 1; }
      else if (s_hi - s_lo <= 1)    { s_T16 = (uint32_t)s_lo; s_done = 1; }
      else if (tot > 1024)          { s_lo = (int)q; }
      else                          { s_hi = (int)q; }
    }
    __syncthreads();
  }
  const uint32_t T16 = s_T16;
  const float w10 = w1[0], w11 = w1[1], w12 = w1[2], w13 = w1[3], w14 = w1[4];

  // collect candidates from register keys; recompute EXACT dot
#pragma unroll
  for (int q = 0; q < 4; ++q) {
    const int nb = 8 * (q * 1024 + tid);
    uint32_t w[4] = { kr[q].x, kr[q].y, kr[q].z, kr[q].w };
#pragma unroll
    for (int j = 0; j < 4; ++j) {
      uint32_t lo = w[j] & 0xFFFFu, hi = w[j] >> 16;
      if (lo >= T16) {
        int p = atomicAdd(&s_cnt, 1);
        if (p < 1024) {
          int i = nb + 2 * j;
          const float* r = xg + (size_t)i * L1;
          float dv = r[0]*w10 + r[1]*w11 + r[2]*w12 + r[3]*w13 + r[4]*w14;
          comp[p] = ((unsigned long long)mono(dv) << 16) | (unsigned)(65535 - i);
        }
      }
      if (hi >= T16) {
        int p = atomicAdd(&s_cnt, 1);
        if (p < 1024) {
          int i = nb + 2 * j + 1;
          const float* r = xg + (size_t)i * L1;
          float dv = r[0]*w10 + r[1]*w11 + r[2]*w12 + r[3]*w13 + r[4]*w14;
          comp[p] = ((unsigned long long)mono(dv) << 16) | (unsigned)(65535 - i);
        }
      }
    }
  }
  __syncthreads();
  int cnt = s_cnt; if (cnt > 1024) cnt = 1024;
  const int nrk = (cnt <= 512) ? 512 : 1024;
  for (int i = tid; i < nrk; i += 1024)
    if (i >= cnt) comp[i] = 0ULL;
  __syncthreads();
  if (tid < nrk) {   // unrolled broadcast counting-rank
    unsigned long long c = comp[tid];
    int r = 0;
    for (int i = 0; i < nrk; i += 8) {
      ulonglong2 v0 = *(const ulonglong2*)&comp[i];
      ulonglong2 v1 = *(const ulonglong2*)&comp[i + 2];
      ulonglong2 v2 = *(const ulonglong2*)&comp[i + 4];
      ulonglong2 v3 = *(const ulonglong2*)&comp[i + 6];
      r += (v0.x > c) + (v0.y > c) + (v1.x > c) + (v1.y > c) +
           (v2.x > c) + (v2.y > c) + (v3.x > c) + (v3.y > c);
    }
    if (r < K1) sorted[r] = c;
  }
  __syncthreads();

  const float inv1 = s_inv[0], inv2 = s_inv[1], inv3 = s_inv[2];

  // phase E: gather x rows * score1
  for (int p = tid; p < K1 * L1; p += 1024) {
    int j = p / L1, k = p - j * L1;
    unsigned long long c = sorted[j];
    int idx = 65535 - (int)(c & 0xFFFFu);
    float sc = fast_tanh(imono((uint32_t)(c >> 16)) * inv1);
    xsel[p] = xg[(size_t)idx * L1 + k] * sc;
  }
  __syncthreads();
  // RNNCell -> h[328][65-stride]
  for (int p = tid; p < K1 * L2; p += 1024) {
    int row = p >> 6, o = p & 63;
    const float* wr = sWih + o * L1;
    const float* xr = xsel + row * L1;
    float acc = sbih[o];
#pragma unroll
    for (int k = 0; k < L1; ++k) acc += xr[k] * wr[k];
    hbuf[row * 65 + o] = fast_tanh(acc);
  }
  __syncthreads();

  // pool2: scores -> comp[0..384), counting-rank(384) -> sorted
  for (int j = tid; j < 384; j += 1024) {
    unsigned long long c = 0ULL;
    if (j < K1) {
      const float* hr = hbuf + j * 65;
      float acc = 0.f;
      for (int k = 0; k < L2; ++k) acc += hr[k] * sw2v[k];
      c = ((unsigned long long)mono(acc) << 16) | (unsigned)(65535 - j);
    }
    comp[j] = c;
  }
  __syncthreads();
  if (tid < 384) {
    unsigned long long c = comp[tid];
    int r = 0;
    for (int i = 0; i < 384; i += 8) {
      ulonglong2 v0 = *(const ulonglong2*)&comp[i];
      ulonglong2 v1 = *(const ulonglong2*)&comp[i + 2];
      ulonglong2 v2 = *(const ulonglong2*)&comp[i + 4];
      ulonglong2 v3 = *(const ulonglong2*)&comp[i + 6];
      r += (v0.x > c) + (v0.y > c) + (v1.x > c) + (v1.y > c) +
           (v2.x > c) + (v2.y > c) + (v3.x > c) + (v3.y > c);
    }
    sorted[r] = c;
  }
  __syncthreads();

  // phase G: x2[33][65] = h[sel] * score2
  float* x2f = hbuf + K1 * 65;
  for (int p = tid; p < K2 * L2; p += 1024) {
    int j = p >> 6, k = p & 63;
    unsigned long long c = sorted[j];
    int row = 65535 - (int)(c & 0xFFFFu);
    float sc = fast_tanh(imono((uint32_t)(c >> 16)) * inv2);
    x2f[j * 65 + k] = hbuf[row * 65 + k] * sc;
  }
  __syncthreads();

  // phase H: y[33][32] = relu(x2 @ W2^T + b2)
  float* yf = x2f + K2 * 65;  // stride 33
  for (int p = tid; p < K2 * L3; p += 1024) {
    int j = p >> 5, o = p & 31;
    const float* xr = x2f + j * 65;
    const float* wr = sW2 + o * 65;
    float acc = sb2[o];
    for (int k = 0; k < L2; ++k) acc += xr[k] * wr[k];
    yf[j * 33 + o] = fmaxf(acc, 0.f);
  }
  __syncthreads();

  // pool3: scores -> comp[0..64), counting-rank(64) -> sorted
  for (int j = tid; j < 64; j += 1024) {
    unsigned long long c = 0ULL;
    if (j < K2) {
      const float* yr = yf + j * 33;
      float acc = 0.f;
      for (int k = 0; k < L3; ++k) acc += yr[k] * sw3v[k];
      c = ((unsigned long long)mono(acc) << 16) | (unsigned)(65535 - j);
    }
    comp[j] = c;
  }
  __syncthreads();
  if (tid < 64) {
    unsigned long long c = comp[tid];
    int r = 0;
    for (int i = 0; i < 64; i += 8) {
      ulonglong2 v0 = *(const ulonglong2*)&comp[i];
      ulonglong2 v1 = *(const ulonglong2*)&comp[i + 2];
      ulonglong2 v2 = *(const ulonglong2*)&comp[i + 4];
      ulonglong2 v3 = *(const ulonglong2*)&comp[i + 6];
      r += (v0.x > c) + (v0.y > c) + (v1.x > c) + (v1.y > c) +
           (v2.x > c) + (v2.y > c) + (v3.x > c) + (v3.y > c);
    }
    sorted[r] = c;
  }
  __syncthreads();

  // phase J: out[4][8] = (y[sel]*score3) @ W3^T + b3
  for (int p = tid; p < K3 * L4; p += 1024) {
    int t = p >> 3, o = p & 7;
    unsigned long long c = sorted[t];
    int row = 65535 - (int)(c & 0xFFFFu);
    float sc = fast_tanh(imono((uint32_t)(c >> 16)) * inv3);
    const float* yr = yf + row * 33;
    const float* wr = sW3 + o * L3;
    float acc = sb3[o];
    for (int k = 0; k < L3; ++k) acc += yr[k] * sc * wr[k];
    out[((size_t)g * K3 + t) * L4 + o] = acc;
  }
}

extern "C" void kernel_launch(void* const* d_in, const int* in_sizes, int n_in,
                              void* d_out, int out_size, void* d_ws, size_t ws_size,
                              hipStream_t stream) {
  const float* x    = (const float*)d_in[0];
  // d_in[1] = edge_index (unused), d_in[2] = batch (unused: static contiguous grouping)
  const float* w1   = (const float*)d_in[3];
  const float* W_ih = (const float*)d_in[4];
  const float* b_ih = (const float*)d_in[5];
  const float* b_hh = (const float*)d_in[6];
  const float* w2   = (const float*)d_in[7];
  const float* W2   = (const float*)d_in[8];
  const float* b2   = (const float*)d_in[9];
  const float* w3   = (const float*)d_in[10];
  const float* W3   = (const float*)d_in[11];
  const float* b3   = (const float*)d_in[12];
  float* out = (float*)d_out;

  uint32_t* key32 = (uint32_t*)d_ws;   // 8 MB packed key16

  score_kernel<<<dim3(NGRAPH * 16), dim3(256), 0, stream>>>(x, w1, key32);
  selmlp_kernel<<<dim3(NGRAPH), dim3(1024), 0, stream>>>(
      x, key32, w1, W_ih, b_ih, b_hh, w2, W2, b2, w3, W3, b3, out);
}

// Round 12
// 57.795 us; speedup vs baseline: 28.7678x; 1.3880x over previous
//
#include <hip/hip_runtime.h>
#include <stdint.h>
#include <math.h>

constexpr int NPG = 32768;
constexpr int NGRAPH = 128;
constexpr int L1 = 5, L2 = 64, L3 = 32, L4 = 8;
constexpr int K1 = 328, K2 = 33, K3 = 4;

__device__ __forceinline__ uint32_t mono(float f) {
  uint32_t u = __float_as_uint(f);
  return (u & 0x80000000u) ? ~u : (u | 0x80000000u);
}
__device__ __forceinline__ float imono(uint32_t k) {
  uint32_t u = (k & 0x80000000u) ? (k ^ 0x80000000u) : ~k;
  return __uint_as_float(u);
}
// robust fast tanh: 1 - 2/(e^{2x}+1); exact at +/-inf (passed absmax 0.0 in r10/r11)
__device__ __forceinline__ float fast_tanh(float x) {
  float e = __expf(2.0f * x);
  return 1.0f - 2.0f / (e + 1.0f);
}

// ---- kernel 1: DENSE score stream (r8-proven, unchanged) ----
__global__ __launch_bounds__(256) void score_kernel(
    const float* __restrict__ x, const float* __restrict__ w1,
    uint32_t* __restrict__ key32) {
  __shared__ __align__(16) float sb[2048 * L1];   // 40 KB
  const int tid = threadIdx.x;
  const int g = blockIdx.x >> 4;
  const int bg = blockIdx.x & 15;
  const float w10 = w1[0], w11 = w1[1], w12 = w1[2], w13 = w1[3], w14 = w1[4];
  const float4* src = (const float4*)(x + ((size_t)g * NPG + bg * 2048) * L1);
#pragma unroll
  for (int k = 0; k < 10; ++k)
    ((float4*)sb)[tid + 256 * k] = src[tid + 256 * k];
  __syncthreads();
  uint32_t* kg = key32 + (size_t)g * (NPG / 2) + bg * 1024;
#pragma unroll
  for (int p = 0; p < 4; ++p) {
    const int np = tid + 256 * p;                 // word np = nodes 2np (lo16), 2np+1 (hi16)
    const float* r = sb + np * 10;
    float d0 = r[0]*w10 + r[1]*w11 + r[2]*w12 + r[3]*w13 + r[4]*w14;
    float d1 = r[5]*w10 + r[6]*w11 + r[7]*w12 + r[8]*w13 + r[9]*w14;
    kg[np] = (mono(d0) >> 16) | (mono(d1) & 0xFFFF0000u);
  }
}

// ---- kernel 2: analytic-prior threshold (exact-count gated) + MLP ----
__global__ __launch_bounds__(1024, 1) void selmlp_kernel(
    const float* __restrict__ x, const uint32_t* __restrict__ key32,
    const float* __restrict__ w1, const float* __restrict__ W_ih,
    const float* __restrict__ b_ih, const float* __restrict__ b_hh,
    const float* __restrict__ w2, const float* __restrict__ W2,
    const float* __restrict__ b2, const float* __restrict__ w3,
    const float* __restrict__ W3, const float* __restrict__ b3,
    float* __restrict__ out) {
  __shared__ __align__(16) float hbuf[K1 * 65 + K2 * 65 + K2 * 33];  // 98.2 KB
  __shared__ __align__(16) unsigned long long comp[1024];   // 8 KB
  __shared__ __align__(16) unsigned long long sorted[512];  // 4 KB
  __shared__ __align__(16) float fa[4608];                  // 18 KB
  __shared__ int wred[16];
  __shared__ int s_lo, s_hi, s_done, s_cnt;
  __shared__ uint32_t s_T16;
  __shared__ float s_inv[3], s_nw1;

  float* xsel = fa;                  // [K1*L1]
  float* sWih = fa + 1640;
  float* sbih = fa + 1960;           // b_ih + b_hh
  float* sW2  = fa + 2024;           // [L3][65]
  float* sb2  = fa + 4104;
  float* sw2v = fa + 4136;
  float* sw3v = fa + 4200;
  float* sW3  = fa + 4232;
  float* sb3  = fa + 4488;

  const int tid = threadIdx.x;
  const int wid = tid >> 6;
  const int g = blockIdx.x;
  const float* xg = x + (size_t)g * NPG * L1;
  const uint4* k4 = (const uint4*)(key32 + (size_t)g * (NPG / 2));

  // 32 keys per thread in registers; uint4 V covers nodes 8V..8V+7
  uint4 kr[4];
#pragma unroll
  for (int q = 0; q < 4; ++q) kr[q] = k4[q * 1024 + tid];   // coalesced

  // stage weights + norms (overlaps key loads)
  for (int i = tid; i < L2 * L1; i += 1024) sWih[i] = W_ih[i];
  for (int i = tid; i < L2; i += 1024) { sbih[i] = b_ih[i] + b_hh[i]; sw2v[i] = w2[i]; }
  for (int i = tid; i < L3 * L2; i += 1024) sW2[(i >> 6) * 65 + (i & 63)] = W2[i];
  for (int i = tid; i < L3; i += 1024) { sb2[i] = b2[i]; sw3v[i] = w3[i]; }
  for (int i = tid; i < L4 * L3; i += 1024) sW3[i] = W3[i];
  for (int i = tid; i < L4; i += 1024) sb3[i] = b3[i];
  if (tid < 64) {
    float a = (tid < L1) ? w1[tid] : 0.f;
    float b = w2[tid];
    float c = (tid < L3) ? w3[tid] : 0.f;
    a *= a; b *= b; c *= c;
    for (int d = 1; d < 64; d <<= 1) {
      a += __shfl_xor(a, d); b += __shfl_xor(b, d); c += __shfl_xor(c, d);
    }
    if (tid == 0) {
      float nw1 = sqrtf(a);
      s_nw1 = nw1;
      s_inv[0] = 1.f / nw1; s_inv[1] = 1.f / sqrtf(b); s_inv[2] = 1.f / sqrtf(c);
      s_cnt = 0; s_done = 0; s_lo = 0; s_hi = 65536;
    }
  }
  __syncthreads();

  // Threshold probe loop. it=0 uses the ANALYTIC prior: d = x.w1 ~ N(0,||w1||^2)
  // exactly for iid-normal x, so rank-328/32768 sits at z=2.2315 (E[count]=420,
  // sd~20.5; accept window [328,512] is +/-4.5 sd). Acceptance is gated by an
  // EXACT register count, so correctness never depends on the prior; misses
  // fall into the proven binary search. (superset: count(>=T)>=K1 ==> T <=
  // key16 of true rank-K1; monotone trunc preserves order statistics.)
  const uint32_t Tprior = mono(2.2315f * s_nw1) >> 16;
  for (int it = 0; it < 18; ++it) {
    if (s_done) break;                      // uniform (shared)
    const uint32_t q = (it == 0) ? Tprior : (uint32_t)((s_lo + s_hi) >> 1);
    int cc = 0;
#pragma unroll
    for (int qq = 0; qq < 4; ++qq) {
      uint32_t w[4] = { kr[qq].x, kr[qq].y, kr[qq].z, kr[qq].w };
#pragma unroll
      for (int j = 0; j < 4; ++j)
        cc += ((w[j] & 0xFFFFu) >= q) + ((w[j] >> 16) >= q);
    }
    for (int d = 1; d < 64; d <<= 1) cc += __shfl_xor(cc, d);
    if ((tid & 63) == 0) wred[wid] = cc;
    __syncthreads();
    if (tid == 0) {
      int tot = 0;
      for (int w = 0; w < 16; ++w) tot += wred[w];
      if (tot >= K1 && tot <= 512)      { s_T16 = q; s_done = 1; }
      else if (s_hi - s_lo <= 1 && it > 0) { s_T16 = (uint32_t)s_lo; s_done = 1; } // plateau
      else if (tot > 512)               { if ((int)q > s_lo) s_lo = (int)q; }
      else                              { if ((int)q < s_hi) s_hi = (int)q; }
    }
    __syncthreads();
  }
  const uint32_t T16 = s_T16;
  const float w10 = w1[0], w11 = w1[1], w12 = w1[2], w13 = w1[3], w14 = w1[4];

  // collect candidates from register keys; recompute EXACT dot
#pragma unroll
  for (int q = 0; q < 4; ++q) {
    const int nb = 8 * (q * 1024 + tid);
    uint32_t w[4] = { kr[q].x, kr[q].y, kr[q].z, kr[q].w };
#pragma unroll
    for (int j = 0; j < 4; ++j) {
      uint32_t lo = w[j] & 0xFFFFu, hi = w[j] >> 16;
      if (lo >= T16) {
        int p = atomicAdd(&s_cnt, 1);
        if (p < 1024) {
          int i = nb + 2 * j;
          const float* r = xg + (size_t)i * L1;
          float dv = r[0]*w10 + r[1]*w11 + r[2]*w12 + r[3]*w13 + r[4]*w14;
          comp[p] = ((unsigned long long)mono(dv) << 16) | (unsigned)(65535 - i);
        }
      }
      if (hi >= T16) {
        int p = atomicAdd(&s_cnt, 1);
        if (p < 1024) {
          int i = nb + 2 * j + 1;
          const float* r = xg + (size_t)i * L1;
          float dv = r[0]*w10 + r[1]*w11 + r[2]*w12 + r[3]*w13 + r[4]*w14;
          comp[p] = ((unsigned long long)mono(dv) << 16) | (unsigned)(65535 - i);
        }
      }
    }
  }
  __syncthreads();
  int cnt = s_cnt; if (cnt > 1024) cnt = 1024;
  int nrk;
  if (cnt <= 512) { nrk = (cnt + 7) & ~7; if (nrk < 8) nrk = 8; }  // typ. ~424
  else            { nrk = 1024; }                                  // plateau safety
  for (int i = tid; i < nrk; i += 1024)
    if (i >= cnt) comp[i] = 0ULL;
  __syncthreads();
  if (tid < nrk) {   // unrolled broadcast counting-rank, dynamic bound
    unsigned long long c = comp[tid];
    int r = 0;
    for (int i = 0; i < nrk; i += 8) {
      ulonglong2 v0 = *(const ulonglong2*)&comp[i];
      ulonglong2 v1 = *(const ulonglong2*)&comp[i + 2];
      ulonglong2 v2 = *(const ulonglong2*)&comp[i + 4];
      ulonglong2 v3 = *(const ulonglong2*)&comp[i + 6];
      r += (v0.x > c) + (v0.y > c) + (v1.x > c) + (v1.y > c) +
           (v2.x > c) + (v2.y > c) + (v3.x > c) + (v3.y > c);
    }
    if (r < K1) sorted[r] = c;
  }
  __syncthreads();

  const float inv1 = s_inv[0], inv2 = s_inv[1], inv3 = s_inv[2];

  // phase E: gather x rows * score1
  for (int p = tid; p < K1 * L1; p += 1024) {
    int j = p / L1, k = p - j * L1;
    unsigned long long c = sorted[j];
    int idx = 65535 - (int)(c & 0xFFFFu);
    float sc = fast_tanh(imono((uint32_t)(c >> 16)) * inv1);
    xsel[p] = xg[(size_t)idx * L1 + k] * sc;
  }
  __syncthreads();
  // RNNCell -> h[328][65-stride]
  for (int p = tid; p < K1 * L2; p += 1024) {
    int row = p >> 6, o = p & 63;
    const float* wr = sWih + o * L1;
    const float* xr = xsel + row * L1;
    float acc = sbih[o];
#pragma unroll
    for (int k = 0; k < L1; ++k) acc += xr[k] * wr[k];
    hbuf[row * 65 + o] = fast_tanh(acc);
  }
  __syncthreads();

  // pool2: scores -> comp[0..384), counting-rank(384) -> sorted
  for (int j = tid; j < 384; j += 1024) {
    unsigned long long c = 0ULL;
    if (j < K1) {
      const float* hr = hbuf + j * 65;
      float acc = 0.f;
      for (int k = 0; k < L2; ++k) acc += hr[k] * sw2v[k];
      c = ((unsigned long long)mono(acc) << 16) | (unsigned)(65535 - j);
    }
    comp[j] = c;
  }
  __syncthreads();
  if (tid < 384) {
    unsigned long long c = comp[tid];
    int r = 0;
    for (int i = 0; i < 384; i += 8) {
      ulonglong2 v0 = *(const ulonglong2*)&comp[i];
      ulonglong2 v1 = *(const ulonglong2*)&comp[i + 2];
      ulonglong2 v2 = *(const ulonglong2*)&comp[i + 4];
      ulonglong2 v3 = *(const ulonglong2*)&comp[i + 6];
      r += (v0.x > c) + (v0.y > c) + (v1.x > c) + (v1.y > c) +
           (v2.x > c) + (v2.y > c) + (v3.x > c) + (v3.y > c);
    }
    sorted[r] = c;
  }
  __syncthreads();

  // phase G: x2[33][65] = h[sel] * score2
  float* x2f = hbuf + K1 * 65;
  for (int p = tid; p < K2 * L2; p += 1024) {
    int j = p >> 6, k = p & 63;
    unsigned long long c = sorted[j];
    int row = 65535 - (int)(c & 0xFFFFu);
    float sc = fast_tanh(imono((uint32_t)(c >> 16)) * inv2);
    x2f[j * 65 + k] = hbuf[row * 65 + k] * sc;
  }
  __syncthreads();

  // phase H: y[33][32] = relu(x2 @ W2^T + b2)
  float* yf = x2f + K2 * 65;  // stride 33
  for (int p = tid; p < K2 * L3; p += 1024) {
    int j = p >> 5, o = p & 31;
    const float* xr = x2f + j * 65;
    const float* wr = sW2 + o * 65;
    float acc = sb2[o];
    for (int k = 0; k < L2; ++k) acc += xr[k] * wr[k];
    yf[j * 33 + o] = fmaxf(acc, 0.f);
  }
  __syncthreads();

  // pool3: scores -> comp[0..64), counting-rank(64) -> sorted
  for (int j = tid; j < 64; j += 1024) {
    unsigned long long c = 0ULL;
    if (j < K2) {
      const float* yr = yf + j * 33;
      float acc = 0.f;
      for (int k = 0; k < L3; ++k) acc += yr[k] * sw3v[k];
      c = ((unsigned long long)mono(acc) << 16) | (unsigned)(65535 - j);
    }
    comp[j] = c;
  }
  __syncthreads();
  if (tid < 64) {
    unsigned long long c = comp[tid];
    int r = 0;
    for (int i = 0; i < 64; i += 8) {
      ulonglong2 v0 = *(const ulonglong2*)&comp[i];
      ulonglong2 v1 = *(const ulonglong2*)&comp[i + 2];
      ulonglong2 v2 = *(const ulonglong2*)&comp[i + 4];
      ulonglong2 v3 = *(const ulonglong2*)&comp[i + 6];
      r += (v0.x > c) + (v0.y > c) + (v1.x > c) + (v1.y > c) +
           (v2.x > c) + (v2.y > c) + (v3.x > c) + (v3.y > c);
    }
    sorted[r] = c;
  }
  __syncthreads();

  // phase J: out[4][8] = (y[sel]*score3) @ W3^T + b3
  for (int p = tid; p < K3 * L4; p += 1024) {
    int t = p >> 3, o = p & 7;
    unsigned long long c = sorted[t];
    int row = 65535 - (int)(c & 0xFFFFu);
    float sc = fast_tanh(imono((uint32_t)(c >> 16)) * inv3);
    const float* yr = yf + row * 33;
    const float* wr = sW3 + o * L3;
    float acc = sb3[o];
    for (int k = 0; k < L3; ++k) acc += yr[k] * sc * wr[k];
    out[((size_t)g * K3 + t) * L4 + o] = acc;
  }
}

extern "C" void kernel_launch(void* const* d_in, const int* in_sizes, int n_in,
                              void* d_out, int out_size, void* d_ws, size_t ws_size,
                              hipStream_t stream) {
  const float* x    = (const float*)d_in[0];
  // d_in[1] = edge_index (unused), d_in[2] = batch (unused: static contiguous grouping)
  const float* w1   = (const float*)d_in[3];
  const float* W_ih = (const float*)d_in[4];
  const float* b_ih = (const float*)d_in[5];
  const float* b_hh = (const float*)d_in[6];
  const float* w2   = (const float*)d_in[7];
  const float* W2   = (const float*)d_in[8];
  const float* b2   = (const float*)d_in[9];
  const float* w3   = (const float*)d_in[10];
  const float* W3   = (const float*)d_in[11];
  const float* b3   = (const float*)d_in[12];
  float* out = (float*)d_out;

  uint32_t* key32 = (uint32_t*)d_ws;   // 8 MB packed key16

  score_kernel<<<dim3(NGRAPH * 16), dim3(256), 0, stream>>>(x, w1, key32);
  selmlp_kernel<<<dim3(NGRAPH), dim3(1024), 0, stream>>>(
      x, key32, w1, W_ih, b_ih, b_hh, w2, W2, b2, w3, W3, b3, out);
}

// Round 13
// 44.876 us; speedup vs baseline: 37.0498x; 1.2879x over previous
//
#include <hip/hip_runtime.h>
#include <stdint.h>
#include <math.h>

constexpr int NPG = 32768;
constexpr int NGRAPH = 128;
constexpr int L1 = 5, L2 = 64, L3 = 32, L4 = 8;
constexpr int K1 = 328, K2 = 33, K3 = 4;
constexpr int SEGS = 16;     // score blocks per graph
constexpr int CAP  = 64;     // per-segment candidate capacity (E=26, sd=5; max@2048 segs ~46)

__device__ __forceinline__ uint32_t mono(float f) {
  uint32_t u = __float_as_uint(f);
  return (u & 0x80000000u) ? ~u : (u | 0x80000000u);
}
__device__ __forceinline__ float imono(uint32_t k) {
  uint32_t u = (k & 0x80000000u) ? (k ^ 0x80000000u) : ~k;
  return __uint_as_float(u);
}
// robust fast tanh: 1 - 2/(e^{2x}+1); passed absmax 0.0 in r10-r12
__device__ __forceinline__ float fast_tanh(float x) {
  float e = __expf(2.0f * x);
  return 1.0f - 2.0f / (e + 1.0f);
}

// ---- kernel 1: score stream + analytic-threshold compaction ----
// 2048 blocks x 256. T = 2.2315*||w1|| identical across blocks (same serial
// computation on same w1). Writes per-segment count + <=CAP full-precision
// composites ((mono32(d)<<16)|(65535-i)). No atomics across blocks; nothing
// to zero (counts written unconditionally every call).
__global__ __launch_bounds__(256) void score_kernel(
    const float* __restrict__ x, const float* __restrict__ w1,
    int* __restrict__ cnts, unsigned long long* __restrict__ cand) {
  __shared__ __align__(16) float sb[2048 * L1];   // 40 KB
  __shared__ unsigned long long cb[CAP];
  __shared__ int s_n;
  __shared__ float s_tf;
  const int tid = threadIdx.x;
  const int g = blockIdx.x >> 4;
  const int bg = blockIdx.x & 15;
  if (tid == 0) {
    s_n = 0;
    float s = 0.f;
    for (int k = 0; k < L1; ++k) s += w1[k] * w1[k];
    s_tf = 2.2315f * sqrtf(s);   // analytic rank-328/32768 prior (E[count]=420)
  }
  const float w10 = w1[0], w11 = w1[1], w12 = w1[2], w13 = w1[3], w14 = w1[4];
  const float4* src = (const float4*)(x + ((size_t)g * NPG + bg * 2048) * L1);
#pragma unroll
  for (int k = 0; k < 10; ++k)
    ((float4*)sb)[tid + 256 * k] = src[tid + 256 * k];
  __syncthreads();
  const float tf = s_tf;
#pragma unroll
  for (int p = 0; p < 4; ++p) {
    const int np = tid + 256 * p;                 // node pair
    const float* r = sb + np * 10;
    float d0 = r[0]*w10 + r[1]*w11 + r[2]*w12 + r[3]*w13 + r[4]*w14;
    float d1 = r[5]*w10 + r[6]*w11 + r[7]*w12 + r[8]*w13 + r[9]*w14;
    const int i0 = bg * 2048 + 2 * np;            // node index within graph
    if (d0 >= tf) {
      int pos = atomicAdd(&s_n, 1);
      if (pos < CAP)
        cb[pos] = ((unsigned long long)mono(d0) << 16) | (unsigned)(65535 - i0);
    }
    if (d1 >= tf) {
      int pos = atomicAdd(&s_n, 1);
      if (pos < CAP)
        cb[pos] = ((unsigned long long)mono(d1) << 16) | (unsigned)(65535 - (i0 + 1));
    }
  }
  __syncthreads();
  const int n = s_n;
  if (tid == 0) cnts[g * SEGS + bg] = n;          // raw count (selmlp gates on >CAP)
  if (tid < CAP && tid < n)
    cand[((size_t)g * SEGS + bg) * CAP + tid] = cb[tid];
}

// ---- kernel 2: gather pre-thresholded candidates + rank + full MLP ----
__global__ __launch_bounds__(1024, 1) void selmlp_kernel(
    const float* __restrict__ x, const int* __restrict__ cnts,
    const unsigned long long* __restrict__ cand,
    const float* __restrict__ w1, const float* __restrict__ W_ih,
    const float* __restrict__ b_ih, const float* __restrict__ b_hh,
    const float* __restrict__ w2, const float* __restrict__ W2,
    const float* __restrict__ b2, const float* __restrict__ w3,
    const float* __restrict__ W3, const float* __restrict__ b3,
    float* __restrict__ out) {
  __shared__ __align__(16) float hbuf[K1 * 65 + K2 * 65 + K2 * 33];  // 98.2 KB
  __shared__ __align__(16) unsigned long long comp[1024];   // 8 KB
  __shared__ __align__(16) unsigned long long sorted[512];  // 4 KB
  __shared__ __align__(16) float fa[4608];                  // 18 KB
  __shared__ int soff[SEGS + 1];
  __shared__ int wred[16];
  __shared__ int s_fb, s_ctot, s_lo, s_hi, s_done, s_cnt;
  __shared__ uint32_t s_T;
  __shared__ float s_inv[3];

  float* xsel = fa;                  // [K1*L1]
  float* sWih = fa + 1640;
  float* sbih = fa + 1960;           // b_ih + b_hh
  float* sW2  = fa + 2024;           // [L3][65]
  float* sb2  = fa + 4104;
  float* sw2v = fa + 4136;
  float* sw3v = fa + 4200;
  float* sW3  = fa + 4232;
  float* sb3  = fa + 4488;

  const int tid = threadIdx.x;
  const int wid = tid >> 6;
  const int g = blockIdx.x;
  const float* xg = x + (size_t)g * NPG * L1;

  // stage weights + norms
  for (int i = tid; i < L2 * L1; i += 1024) sWih[i] = W_ih[i];
  for (int i = tid; i < L2; i += 1024) { sbih[i] = b_ih[i] + b_hh[i]; sw2v[i] = w2[i]; }
  for (int i = tid; i < L3 * L2; i += 1024) sW2[(i >> 6) * 65 + (i & 63)] = W2[i];
  for (int i = tid; i < L3; i += 1024) { sb2[i] = b2[i]; sw3v[i] = w3[i]; }
  for (int i = tid; i < L4 * L3; i += 1024) sW3[i] = W3[i];
  for (int i = tid; i < L4; i += 1024) sb3[i] = b3[i];
  if (tid < 64) {
    float a = (tid < L1) ? w1[tid] : 0.f;
    float b = w2[tid];
    float c = (tid < L3) ? w3[tid] : 0.f;
    a *= a; b *= b; c *= c;
    for (int d = 1; d < 64; d <<= 1) {
      a += __shfl_xor(a, d); b += __shfl_xor(b, d); c += __shfl_xor(c, d);
    }
    if (tid == 0) {
      s_inv[0] = 1.f / sqrtf(a); s_inv[1] = 1.f / sqrtf(b); s_inv[2] = 1.f / sqrtf(c);
      s_cnt = 0; s_done = 0; s_lo = 0; s_hi = 0;
    }
  }
  if (tid < SEGS) soff[tid] = cnts[g * SEGS + tid];
  __syncthreads();
  if (tid == 0) {   // serial 16-element scan + exactness gate
    int off = 0, fb = 0;
    for (int s2 = 0; s2 < SEGS; ++s2) {
      int c = soff[s2];
      if (c > CAP) fb = 1;
      soff[s2] = off;
      off += c;
    }
    soff[SEGS] = off;
    if (off < K1 || off > 1024) fb = 1;   // prior missed (P~1e-13) -> exact fallback
    s_fb = fb; s_ctot = off;
  }
  __syncthreads();

  if (!s_fb) {
    // gather: wave w copies segment w's candidates (<=64, one wave-read)
    const int wl = tid & 63;
    if (wid < SEGS) {
      const int o = soff[wid], c = soff[wid + 1] - o;
      if (wl < c) comp[o + wl] = cand[((size_t)g * SEGS + wid) * CAP + wl];
    }
    const int ctot = s_ctot;
    const int nrk = (ctot + 7) & ~7;      // typ. ~424
    if (tid >= ctot && tid < nrk) comp[tid] = 0ULL;
    __syncthreads();
    if (tid < nrk) {   // unrolled broadcast counting-rank
      unsigned long long c = comp[tid];
      int r = 0;
      for (int i = 0; i < nrk; i += 8) {
        ulonglong2 v0 = *(const ulonglong2*)&comp[i];
        ulonglong2 v1 = *(const ulonglong2*)&comp[i + 2];
        ulonglong2 v2 = *(const ulonglong2*)&comp[i + 4];
        ulonglong2 v3 = *(const ulonglong2*)&comp[i + 6];
        r += (v0.x > c) + (v0.y > c) + (v1.x > c) + (v1.y > c) +
             (v2.x > c) + (v2.y > c) + (v3.x > c) + (v3.y > c);
      }
      if (r < K1) sorted[r] = c;
    }
    __syncthreads();
  } else {
    // exact fallback (never expected): binary search on mono32 with streamed
    // recompute, then collect + rank. r12-equivalent semantics.
    const float w10 = w1[0], w11 = w1[1], w12 = w1[2], w13 = w1[3], w14 = w1[4];
    if (tid == 0) { s_lo = 0; s_hi = -1; s_done = 0; }  // s_hi=-1 == 2^32 as uint
    __syncthreads();
    for (int it = 0; it < 36; ++it) {
      if (s_done) break;
      const uint32_t lo = (uint32_t)s_lo, hi = (uint32_t)s_hi;
      const uint32_t q = (uint32_t)(((unsigned long long)lo + (unsigned long long)hi) >> 1);
      int cc = 0;
      for (int m = 0; m < 32; ++m) {
        const int i = m * 1024 + tid;
        const float* r = xg + (size_t)i * L1;
        float dv = r[0]*w10 + r[1]*w11 + r[2]*w12 + r[3]*w13 + r[4]*w14;
        cc += (mono(dv) >= q);
      }
      for (int d = 1; d < 64; d <<= 1) cc += __shfl_xor(cc, d);
      if ((tid & 63) == 0) wred[wid] = cc;
      __syncthreads();
      if (tid == 0) {
        int tot = 0;
        for (int w = 0; w < 16; ++w) tot += wred[w];
        if (tot >= K1 && tot <= 1024) { s_T = q; s_done = 1; }
        else if ((uint32_t)s_hi - (uint32_t)s_lo <= 1u) { s_T = (uint32_t)s_lo; s_done = 1; }
        else if (tot > 1024) { s_lo = (int)q; }
        else                 { s_hi = (int)q; }
      }
      __syncthreads();
    }
    const uint32_t T = s_T;
    for (int m = 0; m < 32; ++m) {
      const int i = m * 1024 + tid;
      const float* r = xg + (size_t)i * L1;
      float dv = r[0]*w10 + r[1]*w11 + r[2]*w12 + r[3]*w13 + r[4]*w14;
      if (mono(dv) >= T) {
        int p = atomicAdd(&s_cnt, 1);
        if (p < 1024)
          comp[p] = ((unsigned long long)mono(dv) << 16) | (unsigned)(65535 - i);
      }
    }
    __syncthreads();
    int cnt = s_cnt; if (cnt > 1024) cnt = 1024;
    int nrk = (cnt + 7) & ~7; if (nrk < 8) nrk = 8;
    if (tid >= cnt && tid < nrk) comp[tid] = 0ULL;
    __syncthreads();
    if (tid < nrk) {
      unsigned long long c = comp[tid];
      int r = 0;
      for (int i = 0; i < nrk; i += 8) {
        ulonglong2 v0 = *(const ulonglong2*)&comp[i];
        ulonglong2 v1 = *(const ulonglong2*)&comp[i + 2];
        ulonglong2 v2 = *(const ulonglong2*)&comp[i + 4];
        ulonglong2 v3 = *(const ulonglong2*)&comp[i + 6];
        r += (v0.x > c) + (v0.y > c) + (v1.x > c) + (v1.y > c) +
             (v2.x > c) + (v2.y > c) + (v3.x > c) + (v3.y > c);
      }
      if (r < K1) sorted[r] = c;
    }
    __syncthreads();
  }

  const float inv1 = s_inv[0], inv2 = s_inv[1], inv3 = s_inv[2];

  // phase E: gather x rows * score1
  for (int p = tid; p < K1 * L1; p += 1024) {
    int j = p / L1, k = p - j * L1;
    unsigned long long c = sorted[j];
    int idx = 65535 - (int)(c & 0xFFFFu);
    float sc = fast_tanh(imono((uint32_t)(c >> 16)) * inv1);
    xsel[p] = xg[(size_t)idx * L1 + k] * sc;
  }
  __syncthreads();
  // RNNCell -> h[328][65-stride]
  for (int p = tid; p < K1 * L2; p += 1024) {
    int row = p >> 6, o = p & 63;
    const float* wr = sWih + o * L1;
    const float* xr = xsel + row * L1;
    float acc = sbih[o];
#pragma unroll
    for (int k = 0; k < L1; ++k) acc += xr[k] * wr[k];
    hbuf[row * 65 + o] = fast_tanh(acc);
  }
  __syncthreads();

  // pool2: scores -> comp[0..384), counting-rank(384) -> sorted
  for (int j = tid; j < 384; j += 1024) {
    unsigned long long c = 0ULL;
    if (j < K1) {
      const float* hr = hbuf + j * 65;
      float acc = 0.f;
      for (int k = 0; k < L2; ++k) acc += hr[k] * sw2v[k];
      c = ((unsigned long long)mono(acc) << 16) | (unsigned)(65535 - j);
    }
    comp[j] = c;
  }
  __syncthreads();
  if (tid < 384) {
    unsigned long long c = comp[tid];
    int r = 0;
    for (int i = 0; i < 384; i += 8) {
      ulonglong2 v0 = *(const ulonglong2*)&comp[i];
      ulonglong2 v1 = *(const ulonglong2*)&comp[i + 2];
      ulonglong2 v2 = *(const ulonglong2*)&comp[i + 4];
      ulonglong2 v3 = *(const ulonglong2*)&comp[i + 6];
      r += (v0.x > c) + (v0.y > c) + (v1.x > c) + (v1.y > c) +
           (v2.x > c) + (v2.y > c) + (v3.x > c) + (v3.y > c);
    }
    sorted[r] = c;
  }
  __syncthreads();

  // phase G: x2[33][65] = h[sel] * score2
  float* x2f = hbuf + K1 * 65;
  for (int p = tid; p < K2 * L2; p += 1024) {
    int j = p >> 6, k = p & 63;
    unsigned long long c = sorted[j];
    int row = 65535 - (int)(c & 0xFFFFu);
    float sc = fast_tanh(imono((uint32_t)(c >> 16)) * inv2);
    x2f[j * 65 + k] = hbuf[row * 65 + k] * sc;
  }
  __syncthreads();

  // phase H: y[33][32] = relu(x2 @ W2^T + b2)
  float* yf = x2f + K2 * 65;  // stride 33
  for (int p = tid; p < K2 * L3; p += 1024) {
    int j = p >> 5, o = p & 31;
    const float* xr = x2f + j * 65;
    const float* wr = sW2 + o * 65;
    float acc = sb2[o];
    for (int k = 0; k < L2; ++k) acc += xr[k] * wr[k];
    yf[j * 33 + o] = fmaxf(acc, 0.f);
  }
  __syncthreads();

  // pool3: scores -> comp[0..64), counting-rank(64) -> sorted
  for (int j = tid; j < 64; j += 1024) {
    unsigned long long c = 0ULL;
    if (j < K2) {
      const float* yr = yf + j * 33;
      float acc = 0.f;
      for (int k = 0; k < L3; ++k) acc += yr[k] * sw3v[k];
      c = ((unsigned long long)mono(acc) << 16) | (unsigned)(65535 - j);
    }
    comp[j] = c;
  }
  __syncthreads();
  if (tid < 64) {
    unsigned long long c = comp[tid];
    int r = 0;
    for (int i = 0; i < 64; i += 8) {
      ulonglong2 v0 = *(const ulonglong2*)&comp[i];
      ulonglong2 v1 = *(const ulonglong2*)&comp[i + 2];
      ulonglong2 v2 = *(const ulonglong2*)&comp[i + 4];
      ulonglong2 v3 = *(const ulonglong2*)&comp[i + 6];
      r += (v0.x > c) + (v0.y > c) + (v1.x > c) + (v1.y > c) +
           (v2.x > c) + (v2.y > c) + (v3.x > c) + (v3.y > c);
    }
    sorted[r] = c;
  }
  __syncthreads();

  // phase J: out[4][8] = (y[sel]*score3) @ W3^T + b3
  for (int p = tid; p < K3 * L4; p += 1024) {
    int t = p >> 3, o = p & 7;
    unsigned long long c = sorted[t];
    int row = 65535 - (int)(c & 0xFFFFu);
    float sc = fast_tanh(imono((uint32_t)(c >> 16)) * inv3);
    const float* yr = yf + row * 33;
    const float* wr = sW3 + o * L3;
    float acc = sb3[o];
    for (int k = 0; k < L3; ++k) acc += yr[k] * sc * wr[k];
    out[((size_t)g * K3 + t) * L4 + o] = acc;
  }
}

extern "C" void kernel_launch(void* const* d_in, const int* in_sizes, int n_in,
                              void* d_out, int out_size, void* d_ws, size_t ws_size,
                              hipStream_t stream) {
  const float* x    = (const float*)d_in[0];
  // d_in[1] = edge_index (unused), d_in[2] = batch (unused: static contiguous grouping)
  const float* w1   = (const float*)d_in[3];
  const float* W_ih = (const float*)d_in[4];
  const float* b_ih = (const float*)d_in[5];
  const float* b_hh = (const float*)d_in[6];
  const float* w2   = (const float*)d_in[7];
  const float* W2   = (const float*)d_in[8];
  const float* b2   = (const float*)d_in[9];
  const float* w3   = (const float*)d_in[10];
  const float* W3   = (const float*)d_in[11];
  const float* b3   = (const float*)d_in[12];
  float* out = (float*)d_out;

  int* cnts = (int*)d_ws;                                             // 8 KB
  unsigned long long* cand =
      (unsigned long long*)((char*)d_ws + 8192);                      // 1 MB

  score_kernel<<<dim3(NGRAPH * SEGS), dim3(256), 0, stream>>>(x, w1, cnts, cand);
  selmlp_kernel<<<dim3(NGRAPH), dim3(1024), 0, stream>>>(
      x, cnts, cand, w1, W_ih, b_ih, b_hh, w2, W2, b2, w3, W3, b3, out);
}